// Round 2
// baseline (486.668 us; speedup 1.0000x reference)
//
#include <hip/hip_runtime.h>

// ---------------------------------------------------------------------------
// 2-layer hetero GraphSAGE, bf16-MFMA.
// R8: - CSR layout chunk-grouped: per-chunk totals reduced inside hist_k,
//       16-wide exclusive scan (scan16_k), base2_k grabs bases from its
//       chunk's counter. place_k's scatter now confined to ~500KB per-XCD
//       L2-resident region -> full-line evictions. (R7 showed place_k is
//       write-amplification-bound: 38MB HBM writes for 4MB payload, ILP
//       and occupancy changes were null.)
//     - chunk sizes rounded to x256 so each base2_k block is in one chunk.
//     - Aggregation quad-group (R6), GEMMs B-resident MFMA (R3).
// ---------------------------------------------------------------------------

typedef __attribute__((ext_vector_type(8))) short bfrag;   // 8 bf16 (4 VGPRs)
typedef __attribute__((ext_vector_type(4))) float ffrag;   // 4 fp32 acc
typedef unsigned short u16;
typedef unsigned int u32;

static inline size_t ws_align(size_t x) { return (x + 255) & ~size_t(255); }

__device__ inline u16 f2bf(float f) {
  union { float f; u32 u; } v; v.f = f;
  u32 r = v.u + 0x7fffu + ((v.u >> 16) & 1u);   // round-nearest-even
  return (u16)(r >> 16);
}
__device__ inline u32 pack2(float a, float b) {
  return (u32)f2bf(a) | ((u32)f2bf(b) << 16);
}
__device__ inline float bf_lo(u32 p) {
  union { u32 u; float f; } v; v.u = p << 16; return v.f;
}
__device__ inline float bf_hi(u32 p) {
  union { u32 u; float f; } v; v.u = p & 0xffff0000u; return v.f;
}

// ---- fused prep: zero counters, conv weights, conv songs, gather playlists -
__global__ __launch_bounds__(256) void prep_k(
    const float* __restrict__ w0, const float* __restrict__ w1,
    const float* __restrict__ w2, const float* __restrict__ w3,
    const float* __restrict__ w4, const float* __restrict__ w5,
    const float* __restrict__ w6, const float* __restrict__ w7,
    u16* __restrict__ Wt,
    const float* __restrict__ song_x, u16* __restrict__ xs, int ns4,
    const float* __restrict__ emb, const int* __restrict__ pid,
    u16* __restrict__ xp, int np,
    int* __restrict__ zero_region, int nzero)
{
  int g0 = blockIdx.x * 256 + threadIdx.x;
  int gs = gridDim.x * 256;
  for (int i = g0; i < nzero; i += gs) zero_region[i] = 0;
  const float* ws[8] = {w0, w1, w2, w3, w4, w5, w6, w7};
  for (int idx = g0; idx < 8 * 16384; idx += gs) {
    int m = idx >> 14, rem = idx & 16383;
    int n = rem >> 7, k = rem & 127;
    Wt[idx] = f2bf(ws[m][k * 128 + n]);
  }
  for (int i = g0; i < ns4; i += gs) {
    float4 v = ((const float4*)song_x)[i];
    ushort4 o;
    o.x = f2bf(v.x); o.y = f2bf(v.y); o.z = f2bf(v.z); o.w = f2bf(v.w);
    ((ushort4*)xs)[i] = o;
  }
  for (int i = g0; i < np * 32; i += gs) {
    int node = i >> 5, q = i & 31;
    float4 v = ((const float4*)(emb + (size_t)pid[node] * 128))[q];
    ushort4 o;
    o.x = f2bf(v.x); o.y = f2bf(v.y); o.z = f2bf(v.z); o.w = f2bf(v.w);
    ((ushort4*)(xp + (size_t)node * 128))[q] = o;
  }
}

// ---- CSR build (XCD-chunked: chunk id = blockIdx&7) ------------------------
// 4-wide int4 edge sweep; per-chunk edge totals reduced into ctot[16]
// (ctot[0..7] = playlist chunks, ctot[8..15] = song chunks).
__global__ __launch_bounds__(256) void hist_k(
    const int* __restrict__ es, const int* __restrict__ ep,
    int* __restrict__ cnt_s, int* __restrict__ cnt_p,
    int* __restrict__ ctot,
    int e, int pch, int sch)
{
  __shared__ int shp, shs;
  if (threadIdx.x == 0) { shp = 0; shs = 0; }
  __syncthreads();
  int j = blockIdx.x & 7;
  int g = blockIdx.x >> 3;
  int nb = gridDim.x >> 3;
  int p_lo = j * pch, s_lo = j * sch;
  int e4 = e >> 2;
  int gs = nb * 256;
  int mp = 0, ms = 0;
  for (int i = g * 256 + threadIdx.x; i < e4; i += gs) {
    int4 p4 = ((const int4*)ep)[i];
    int4 s4 = ((const int4*)es)[i];
    if ((u32)(p4.x - p_lo) < (u32)pch) { atomicAdd(&cnt_p[p4.x], 1); mp++; }
    if ((u32)(p4.y - p_lo) < (u32)pch) { atomicAdd(&cnt_p[p4.y], 1); mp++; }
    if ((u32)(p4.z - p_lo) < (u32)pch) { atomicAdd(&cnt_p[p4.z], 1); mp++; }
    if ((u32)(p4.w - p_lo) < (u32)pch) { atomicAdd(&cnt_p[p4.w], 1); mp++; }
    if ((u32)(s4.x - s_lo) < (u32)sch) { atomicAdd(&cnt_s[s4.x], 1); ms++; }
    if ((u32)(s4.y - s_lo) < (u32)sch) { atomicAdd(&cnt_s[s4.y], 1); ms++; }
    if ((u32)(s4.z - s_lo) < (u32)sch) { atomicAdd(&cnt_s[s4.z], 1); ms++; }
    if ((u32)(s4.w - s_lo) < (u32)sch) { atomicAdd(&cnt_s[s4.w], 1); ms++; }
  }
  if (g == 0 && threadIdx.x == 0) {
    for (int i = e4 << 2; i < e; i++) {
      int p = ep[i], s = es[i];
      if ((u32)(p - p_lo) < (u32)pch) { atomicAdd(&cnt_p[p], 1); mp++; }
      if ((u32)(s - s_lo) < (u32)sch) { atomicAdd(&cnt_s[s], 1); ms++; }
    }
  }
  if (mp) atomicAdd(&shp, mp);
  if (ms) atomicAdd(&shs, ms);
  __syncthreads();
  if (threadIdx.x == 0) {
    if (shp) atomicAdd(&ctot[j], shp);
    if (shs) atomicAdd(&ctot[8 + j], shs);
  }
}

// ---- tiny 16-element exclusive scan: chunk bases into gcnt8 ----------------
__global__ void scan16_k(const int* __restrict__ ctot, int* __restrict__ gcnt8)
{
  if (threadIdx.x == 0 && blockIdx.x == 0) {
    int acc = 0;
    for (int j = 0; j < 8; j++) { gcnt8[j] = acc; acc += ctot[j]; }
    acc = 0;
    for (int j = 0; j < 8; j++) { gcnt8[8 + j] = acc; acc += ctot[8 + j]; }
  }
}

// Per-block scan; block base grabbed from its CHUNK's counter so each
// chunk's CSR positions are contiguous (place_k scatter stays in-L2).
__global__ __launch_bounds__(256) void base2_k(
    const int* __restrict__ cnt_p, int* __restrict__ base_p, int* __restrict__ cur_p,
    const int* __restrict__ cnt_s, int* __restrict__ base_s, int* __restrict__ cur_s,
    int* __restrict__ gcnt8, int np, int ns, int nbp, int pch, int sch)
{
  __shared__ int sh[256];
  __shared__ int bb;
  int t = threadIdx.x;
  const int* cnt; int* base; int* cur; int* gc; int n; int i;
  if ((int)blockIdx.x < nbp) {
    int i0 = blockIdx.x * 256;
    cnt = cnt_p; base = base_p; cur = cur_p; n = np;
    gc = &gcnt8[i0 / pch];
    i = i0 + t;
  } else {
    int i0 = (blockIdx.x - nbp) * 256;
    cnt = cnt_s; base = base_s; cur = cur_s; n = ns;
    gc = &gcnt8[8 + i0 / sch];
    i = i0 + t;
  }
  int v = (i < n) ? cnt[i] : 0;
  sh[t] = v;
  __syncthreads();
  for (int off = 1; off < 256; off <<= 1) {
    int tv = (t >= off) ? sh[t - off] : 0;
    __syncthreads();
    sh[t] += tv;
    __syncthreads();
  }
  if (t == 255) bb = atomicAdd(gc, sh[255]);
  __syncthreads();
  if (i < n) {
    int e = bb + sh[t] - v;
    base[i] = e;
    cur[i] = e;
  }
}

// 4-wide int4 edge sweep (4 independent atomic+scatter chains/thread).
// With chunk-grouped CSR, chunk j's scatter region (~E/8 entries per side)
// lives in XCD j's L2 -> full-line evictions, no 16x write amplification.
__global__ __launch_bounds__(256) void place_k(
    const int* __restrict__ es, const int* __restrict__ ep,
    int* __restrict__ cur_s, int* __restrict__ cur_p,
    int* __restrict__ csr_s, int* __restrict__ csr_p,
    int e, int pch, int sch)
{
  int j = blockIdx.x & 7;
  int g = blockIdx.x >> 3;
  int nb = gridDim.x >> 3;
  int p_lo = j * pch, s_lo = j * sch;
  int e4 = e >> 2;
  int gs = nb * 256;
  for (int i = g * 256 + threadIdx.x; i < e4; i += gs) {
    int4 p4 = ((const int4*)ep)[i];
    int4 s4 = ((const int4*)es)[i];
    if ((u32)(p4.x - p_lo) < (u32)pch) csr_p[atomicAdd(&cur_p[p4.x], 1)] = s4.x;
    if ((u32)(p4.y - p_lo) < (u32)pch) csr_p[atomicAdd(&cur_p[p4.y], 1)] = s4.y;
    if ((u32)(p4.z - p_lo) < (u32)pch) csr_p[atomicAdd(&cur_p[p4.z], 1)] = s4.z;
    if ((u32)(p4.w - p_lo) < (u32)pch) csr_p[atomicAdd(&cur_p[p4.w], 1)] = s4.w;
    if ((u32)(s4.x - s_lo) < (u32)sch) csr_s[atomicAdd(&cur_s[s4.x], 1)] = p4.x;
    if ((u32)(s4.y - s_lo) < (u32)sch) csr_s[atomicAdd(&cur_s[s4.y], 1)] = p4.y;
    if ((u32)(s4.z - s_lo) < (u32)sch) csr_s[atomicAdd(&cur_s[s4.z], 1)] = p4.z;
    if ((u32)(s4.w - s_lo) < (u32)sch) csr_s[atomicAdd(&cur_s[s4.w], 1)] = p4.w;
  }
  if (g == 0 && threadIdx.x == 0) {
    for (int i = e4 << 2; i < e; i++) {
      int p = ep[i], s = es[i];
      if ((u32)(p - p_lo) < (u32)pch) csr_p[atomicAdd(&cur_p[p], 1)] = s;
      if ((u32)(s - s_lo) < (u32)sch) csr_s[atomicAdd(&cur_s[s], 1)] = p;
    }
  }
}

// ---- quad-group mean aggregation with fused post-add -----------------------
// One 16-lane group per dst row: block 256 = 16 rows concurrently in flight.
// out[v] = act( mean_{u in csr[v]} feat[u] (+ post[v]) ), post bf16.
__global__ __launch_bounds__(256) void agg_quad_post_k(
    const u16* __restrict__ feat, const int* __restrict__ csr,
    const int* __restrict__ base, const int* __restrict__ cnt,
    const u16* __restrict__ post,
    void* __restrict__ out, int outF32, int doRelu, int n)
{
  int lr = threadIdx.x & 15;
  int grp = threadIdx.x >> 4;           // 0..15
  int gv = blockIdx.x * 16 + grp;
  if (gv >= n) return;
  int b = base[gv], c = cnt[gv];
  float s0=0,s1=0,s2=0,s3=0,s4=0,s5=0,s6=0,s7=0;
  for (int i = 0; i < c; i += 8) {
    int m = c - i;
    int idx[8];
#pragma unroll
    for (int u = 0; u < 8; u++) idx[u] = csr[b + i + min(u, m - 1)];
#pragma unroll
    for (int u = 0; u < 8; u++) {
      uint4 v = ((const uint4*)(feat + (size_t)idx[u] * 128))[lr];
      if (u < m) {
        s0 += bf_lo(v.x); s1 += bf_hi(v.x);
        s2 += bf_lo(v.y); s3 += bf_hi(v.y);
        s4 += bf_lo(v.z); s5 += bf_hi(v.z);
        s6 += bf_lo(v.w); s7 += bf_hi(v.w);
      }
    }
  }
  float inv = (c > 0) ? 1.0f / (float)c : 0.0f;
  s0 *= inv; s1 *= inv; s2 *= inv; s3 *= inv;
  s4 *= inv; s5 *= inv; s6 *= inv; s7 *= inv;
  if (post) {
    uint4 p = ((const uint4*)(post + (size_t)gv * 128))[lr];
    s0 += bf_lo(p.x); s1 += bf_hi(p.x);
    s2 += bf_lo(p.y); s3 += bf_hi(p.y);
    s4 += bf_lo(p.z); s5 += bf_hi(p.z);
    s6 += bf_lo(p.w); s7 += bf_hi(p.w);
  }
  if (doRelu) {
    s0 = fmaxf(s0, 0.f); s1 = fmaxf(s1, 0.f);
    s2 = fmaxf(s2, 0.f); s3 = fmaxf(s3, 0.f);
    s4 = fmaxf(s4, 0.f); s5 = fmaxf(s5, 0.f);
    s6 = fmaxf(s6, 0.f); s7 = fmaxf(s7, 0.f);
  }
  if (outF32) {
    float* op = (float*)out + (size_t)gv * 128 + lr * 8;
    *(float4*)op = make_float4(s0, s1, s2, s3);
    *(float4*)(op + 4) = make_float4(s4, s5, s6, s7);
  } else {
    uint4 o;
    o.x = pack2(s0, s1); o.y = pack2(s2, s3);
    o.z = pack2(s4, s5); o.w = pack2(s6, s7);
    ((uint4*)((u16*)out + (size_t)gv * 128))[lr] = o;
  }
}

// ---- B-resident MFMA GEMM --------------------------------------------------
// C[M,128] = act( A@W (+Dadd_f32) (+bias) ), K=128, Wt = [n][k] bf16.
__global__ __launch_bounds__(256, 2) void gemm_breg_k(
    const u16* __restrict__ A, const u16* __restrict__ Wt,
    const float* __restrict__ bias, const float* __restrict__ Dadd,
    void* __restrict__ Cout, int M, int doRelu, int outF32)
{
  int lane = threadIdx.x & 63;
  int r = lane & 15, q = lane >> 4;
  int wid = (blockIdx.x * 256 + threadIdx.x) >> 6;
  int nw = gridDim.x * 4;

  bfrag B[4][8];
#pragma unroll
  for (int k0 = 0; k0 < 4; k0++)
#pragma unroll
    for (int j = 0; j < 8; j++)
      B[k0][j] = *(const bfrag*)(Wt + (size_t)(j * 16 + r) * 128 + k0 * 32 + q * 8);

  for (int strip = wid; strip * 16 < M; strip += nw) {
    const u16* arow = A + (size_t)(strip * 16 + r) * 128 + q * 8;
    bfrag a0 = *(const bfrag*)(arow);
    bfrag a1 = *(const bfrag*)(arow + 32);
    bfrag a2 = *(const bfrag*)(arow + 64);
    bfrag a3 = *(const bfrag*)(arow + 96);

    ffrag acc[8];
#pragma unroll
    for (int j = 0; j < 8; j++) acc[j] = (ffrag)0.f;
#pragma unroll
    for (int j = 0; j < 8; j++)
      acc[j] = __builtin_amdgcn_mfma_f32_16x16x32_bf16(B[0][j], a0, acc[j], 0, 0, 0);
#pragma unroll
    for (int j = 0; j < 8; j++)
      acc[j] = __builtin_amdgcn_mfma_f32_16x16x32_bf16(B[1][j], a1, acc[j], 0, 0, 0);
#pragma unroll
    for (int j = 0; j < 8; j++)
      acc[j] = __builtin_amdgcn_mfma_f32_16x16x32_bf16(B[2][j], a2, acc[j], 0, 0, 0);
#pragma unroll
    for (int j = 0; j < 8; j++)
      acc[j] = __builtin_amdgcn_mfma_f32_16x16x32_bf16(B[3][j], a3, acc[j], 0, 0, 0);

    size_t row = (size_t)(strip * 16 + r);
#pragma unroll
    for (int j = 0; j < 8; j++) {
      int col0 = j * 16 + q * 4;
      float v0 = acc[j][0], v1 = acc[j][1], v2 = acc[j][2], v3 = acc[j][3];
      if (bias) {
        float4 bv = *(const float4*)(bias + col0);
        v0 += bv.x; v1 += bv.y; v2 += bv.z; v3 += bv.w;
      }
      if (Dadd) {
        float4 dv = *(const float4*)(Dadd + row * 128 + col0);
        v0 += dv.x; v1 += dv.y; v2 += dv.z; v3 += dv.w;
      }
      if (doRelu) {
        v0 = fmaxf(v0, 0.f); v1 = fmaxf(v1, 0.f);
        v2 = fmaxf(v2, 0.f); v3 = fmaxf(v3, 0.f);
      }
      if (outF32) {
        *(float4*)((float*)Cout + row * 128 + col0) = make_float4(v0, v1, v2, v3);
      } else {
        ushort4 o;
        o.x = f2bf(v0); o.y = f2bf(v1); o.z = f2bf(v2); o.w = f2bf(v3);
        *(ushort4*)((u16*)Cout + row * 128 + col0) = o;
      }
    }
  }
}

// ---------------------------------------------------------------------------

extern "C" void kernel_launch(void* const* d_in, const int* in_sizes, int n_in,
                              void* d_out, int out_size, void* d_ws, size_t ws_size,
                              hipStream_t stream)
{
  const float* song_x = (const float*)d_in[0];
  const int*   pid    = (const int*)d_in[1];
  const int*   e_song = (const int*)d_in[2];
  const int*   e_play = (const int*)d_in[3];
  const float* emb    = (const float*)d_in[4];
  const float* Wl1_sp = (const float*)d_in[5];
  const float* Wr1_sp = (const float*)d_in[6];
  const float* b1_sp  = (const float*)d_in[7];
  const float* Wl1_ps = (const float*)d_in[8];
  const float* Wr1_ps = (const float*)d_in[9];
  const float* b1_ps  = (const float*)d_in[10];
  const float* Wl2_sp = (const float*)d_in[11];
  const float* Wr2_sp = (const float*)d_in[12];
  const float* b2_sp  = (const float*)d_in[13];
  const float* Wl2_ps = (const float*)d_in[14];
  const float* Wr2_ps = (const float*)d_in[15];
  const float* b2_ps  = (const float*)d_in[16];

  const int NS = in_sizes[0] / 128;
  const int NP = in_sizes[1];
  const int E  = in_sizes[2];

  char* w = (char*)d_ws;
  auto alloc = [&](size_t bytes) { char* p = w; w += ws_align(bytes); return p; };
  u16* x_play = (u16*)alloc((size_t)NP * 128 * 2);
  u16* Ms     = (u16*)alloc((size_t)NP * 128 * 2);
  u16* yp     = (u16*)alloc((size_t)NP * 128 * 2);
  u16* p1     = (u16*)alloc((size_t)NP * 128 * 2);
  u16* s1     = (u16*)alloc((size_t)NS * 128 * 2);
  u16* xs     = (u16*)alloc((size_t)NS * 128 * 2);
  u16* Gs     = (u16*)alloc((size_t)NS * 128 * 2);
  float* Gp   = (float*)alloc((size_t)NP * 128 * 4);
  u16* Wt     = (u16*)alloc((size_t)8 * 16384 * 2);  // [mat][n][k]
  int* cnt_p = (int*)alloc(((size_t)NP + NS + 2 + 32) * 4);
  int* cnt_s = cnt_p + NP;
  int* gcnt  = cnt_s + NS;       // 2 ints (legacy slot)
  int* ctot  = gcnt + 2;         // 16 ints: per-chunk edge totals
  int* gcnt8 = ctot + 16;        // 16 ints: per-chunk running base counters
  int* base_p = (int*)alloc((size_t)NP * 4);
  int* cur_p  = (int*)alloc((size_t)NP * 4);
  int* base_s = (int*)alloc((size_t)NS * 4);
  int* cur_s  = (int*)alloc((size_t)NS * 4);
  int* csr_p  = (int*)alloc((size_t)E * 4);
  int* csr_s  = (int*)alloc((size_t)E * 4);

  float* s2_out = (float*)d_out;
  float* p2_out = (float*)d_out + (size_t)NS * 128;

  u16* Wt_l1sp = Wt + 0 * 16384;
  u16* Wt_r1sp = Wt + 1 * 16384;
  u16* Wt_l1ps = Wt + 2 * 16384;
  u16* Wt_r1ps = Wt + 3 * 16384;
  u16* Wt_l2sp = Wt + 4 * 16384;
  u16* Wt_r2sp = Wt + 5 * 16384;
  u16* Wt_l2ps = Wt + 6 * 16384;
  u16* Wt_r2ps = Wt + 7 * 16384;

  // chunk sizes: ceil(n/8) rounded up to x256 so base2_k blocks don't straddle
  const int pch = (((NP + 7) / 8) + 255) & ~255;
  const int sch = (((NS + 7) / 8) + 255) & ~255;
  const int edge_grid = 8 * 128;
  auto ggrid = [](int M) { int s = M / 16; return (s + 7) / 8; };
  const int gP = ggrid(NP), gS = ggrid(NS);
  const int aggP_b = (NP + 15) / 16, aggS_b = (NS + 15) / 16;
  const int nbp = (NP + 255) / 256, nbs = (NS + 255) / 256;

  // ---- prep + CSR build ----
  prep_k<<<1024, 256, 0, stream>>>(Wl1_sp, Wr1_sp, Wl1_ps, Wr1_ps,
                                   Wl2_sp, Wr2_sp, Wl2_ps, Wr2_ps, Wt,
                                   song_x, xs, NS * 32,
                                   emb, pid, x_play, NP,
                                   cnt_p, NP + NS + 2 + 32);
  hist_k<<<edge_grid, 256, 0, stream>>>(e_song, e_play, cnt_s, cnt_p, ctot,
                                        E, pch, sch);
  scan16_k<<<1, 64, 0, stream>>>(ctot, gcnt8);
  base2_k<<<nbp + nbs, 256, 0, stream>>>(cnt_p, base_p, cur_p,
                                         cnt_s, base_s, cur_s, gcnt8,
                                         NP, NS, nbp, pch, sch);
  place_k<<<edge_grid, 256, 0, stream>>>(e_song, e_play, cur_s, cur_p,
                                         csr_s, csr_p, E, pch, sch);

  // ---- layer 1 ----
  // Ms = mean_p(xs)
  agg_quad_post_k<<<aggP_b, 256, 0, stream>>>(xs, csr_p, base_p, cnt_p,
                                              nullptr, Ms, 0, 0, NP);
  // yp = x_play@Wl1_ps
  gemm_breg_k<<<gP, 256, 0, stream>>>(x_play, Wt_l1ps, nullptr, nullptr,
                                      yp, NP, 0, 0);
  // Gs = xs@Wr1_ps + b1_ps (bf16)
  gemm_breg_k<<<gS, 256, 0, stream>>>(xs, Wt_r1ps, b1_ps, nullptr,
                                      (void*)Gs, NS, 0, 0);
  // s1 = relu(mean_s(yp) + Gs)
  agg_quad_post_k<<<aggS_b, 256, 0, stream>>>(yp, csr_s, base_s, cnt_s,
                                              Gs, s1, 0, 1, NS);
  // Gp = Ms@Wl1_sp (fp32)
  gemm_breg_k<<<gP, 256, 0, stream>>>(Ms, Wt_l1sp, nullptr, nullptr,
                                      (void*)Gp, NP, 0, 1);
  // p1 = relu(x_play@Wr1_sp + b1_sp + Gp)
  gemm_breg_k<<<gP, 256, 0, stream>>>(x_play, Wt_r1sp, b1_sp, Gp,
                                      p1, NP, 1, 0);

  // ---- layer 2 ----
  // Ms = mean_p(s1)
  agg_quad_post_k<<<aggP_b, 256, 0, stream>>>(s1, csr_p, base_p, cnt_p,
                                              nullptr, Ms, 0, 0, NP);
  // yp = p1@Wl2_ps
  gemm_breg_k<<<gP, 256, 0, stream>>>(p1, Wt_l2ps, nullptr, nullptr,
                                      yp, NP, 0, 0);
  // Gs = s1@Wr2_ps + b2_ps (bf16)
  gemm_breg_k<<<gS, 256, 0, stream>>>(s1, Wt_r2ps, b2_ps, nullptr,
                                      (void*)Gs, NS, 0, 0);
  // s2 = mean_s(yp) + Gs  (fp32 out)
  agg_quad_post_k<<<aggS_b, 256, 0, stream>>>(yp, csr_s, base_s, cnt_s,
                                              Gs, s2_out, 1, 0, NS);
  // Gp = Ms@Wl2_sp (fp32)
  gemm_breg_k<<<gP, 256, 0, stream>>>(Ms, Wt_l2sp, nullptr, nullptr,
                                      (void*)Gp, NP, 0, 1);
  // p2 = p1@Wr2_sp + b2_sp + Gp (fp32 out)
  gemm_breg_k<<<gP, 256, 0, stream>>>(p1, Wt_r2sp, b2_sp, Gp,
                                      p2_out, NP, 0, 1);
}

// Round 3
// 475.995 us; speedup vs baseline: 1.0224x; 1.0224x over previous
//
#include <hip/hip_runtime.h>

// ---------------------------------------------------------------------------
// 2-layer hetero GraphSAGE, bf16-MFMA.
// R9: - R8 counters proved hist/place are bound by device-scope atomic
//       write-through (hist: 31MB WRITE = 1M atomics x 32B, zero stores).
//       ILP/occupancy/CSR-layout are null levers against that wall.
//     - Strategy: HIDE the atomic wall under independent work via fat
//       kernels (block-range dispatch):
//         L1: prep || hist   L3: place || gemm(yp1) || gemm(Gs1)
//         L4: agg(s1) || agg(Ms1)      L5: gemm(Gs2) || gemm(Gp1)
//         L6: gemm(p1) || agg(Ms2)     L7: gemm(yp2) || gemm(Gp2)
//         L8: gemm(p2) || agg(s2)
//     - hist/place single-pass (reads 32MB->4MB; drop R8 ctot/scan16).
//     - cnt zeroing via hipMemsetAsync (capture-safe; harness uses it).
//     - 17 launches -> 9. Agg quad-group (R6), GEMM B-resident MFMA (R3).
// ---------------------------------------------------------------------------

typedef __attribute__((ext_vector_type(8))) short bfrag;   // 8 bf16 (4 VGPRs)
typedef __attribute__((ext_vector_type(4))) float ffrag;   // 4 fp32 acc
typedef unsigned short u16;
typedef unsigned int u32;

static inline size_t ws_align(size_t x) { return (x + 255) & ~size_t(255); }

__device__ inline u16 f2bf(float f) {
  union { float f; u32 u; } v; v.f = f;
  u32 r = v.u + 0x7fffu + ((v.u >> 16) & 1u);   // round-nearest-even
  return (u16)(r >> 16);
}
__device__ inline u32 pack2(float a, float b) {
  return (u32)f2bf(a) | ((u32)f2bf(b) << 16);
}
__device__ inline float bf_lo(u32 p) {
  union { u32 u; float f; } v; v.u = p << 16; return v.f;
}
__device__ inline float bf_hi(u32 p) {
  union { u32 u; float f; } v; v.u = p & 0xffff0000u; return v.f;
}

// ======================= device work units =================================

// prep: weight transpose+cast, song cast, playlist gather+cast (no zeroing)
__device__ inline void d_prep(int bid, int nb,
    const float* w0, const float* w1, const float* w2, const float* w3,
    const float* w4, const float* w5, const float* w6, const float* w7,
    u16* Wt, const float* song_x, u16* xs, int ns4,
    const float* emb, const int* pid, u16* xp, int np)
{
  int g0 = bid * 256 + threadIdx.x;
  int gs = nb * 256;
  const float* ws[8] = {w0, w1, w2, w3, w4, w5, w6, w7};
  for (int idx = g0; idx < 8 * 16384; idx += gs) {
    int m = idx >> 14, rem = idx & 16383;
    int n = rem >> 7, k = rem & 127;
    Wt[idx] = f2bf(ws[m][k * 128 + n]);
  }
  for (int i = g0; i < ns4; i += gs) {
    float4 v = ((const float4*)song_x)[i];
    ushort4 o;
    o.x = f2bf(v.x); o.y = f2bf(v.y); o.z = f2bf(v.z); o.w = f2bf(v.w);
    ((ushort4*)xs)[i] = o;
  }
  for (int i = g0; i < np * 32; i += gs) {
    int node = i >> 5, q = i & 31;
    float4 v = ((const float4*)(emb + (size_t)pid[node] * 128))[q];
    ushort4 o;
    o.x = f2bf(v.x); o.y = f2bf(v.y); o.z = f2bf(v.z); o.w = f2bf(v.w);
    ((ushort4*)(xp + (size_t)node * 128))[q] = o;
  }
}

// single-pass degree histogram (2 atomics/edge)
__device__ inline void d_hist(int bid, int nb,
    const int* es, const int* ep, int* cnt_s, int* cnt_p, int e)
{
  int e4 = e >> 2;
  int gs = nb * 256;
  for (int i = bid * 256 + threadIdx.x; i < e4; i += gs) {
    int4 p4 = ((const int4*)ep)[i];
    int4 s4 = ((const int4*)es)[i];
    atomicAdd(&cnt_p[p4.x], 1); atomicAdd(&cnt_p[p4.y], 1);
    atomicAdd(&cnt_p[p4.z], 1); atomicAdd(&cnt_p[p4.w], 1);
    atomicAdd(&cnt_s[s4.x], 1); atomicAdd(&cnt_s[s4.y], 1);
    atomicAdd(&cnt_s[s4.z], 1); atomicAdd(&cnt_s[s4.w], 1);
  }
  if (bid == 0 && threadIdx.x == 0) {
    for (int i = e4 << 2; i < e; i++) {
      atomicAdd(&cnt_p[ep[i]], 1);
      atomicAdd(&cnt_s[es[i]], 1);
    }
  }
}

// single-pass counting-sort scatter
__device__ inline void d_place(int bid, int nb,
    const int* es, const int* ep, int* cur_s, int* cur_p,
    int* csr_s, int* csr_p, int e)
{
  int e4 = e >> 2;
  int gs = nb * 256;
  for (int i = bid * 256 + threadIdx.x; i < e4; i += gs) {
    int4 p4 = ((const int4*)ep)[i];
    int4 s4 = ((const int4*)es)[i];
    csr_p[atomicAdd(&cur_p[p4.x], 1)] = s4.x;
    csr_p[atomicAdd(&cur_p[p4.y], 1)] = s4.y;
    csr_p[atomicAdd(&cur_p[p4.z], 1)] = s4.z;
    csr_p[atomicAdd(&cur_p[p4.w], 1)] = s4.w;
    csr_s[atomicAdd(&cur_s[s4.x], 1)] = p4.x;
    csr_s[atomicAdd(&cur_s[s4.y], 1)] = p4.y;
    csr_s[atomicAdd(&cur_s[s4.z], 1)] = p4.z;
    csr_s[atomicAdd(&cur_s[s4.w], 1)] = p4.w;
  }
  if (bid == 0 && threadIdx.x == 0) {
    for (int i = e4 << 2; i < e; i++) {
      csr_p[atomicAdd(&cur_p[ep[i]], 1)] = es[i];
      csr_s[atomicAdd(&cur_s[es[i]], 1)] = ep[i];
    }
  }
}

// quad-group mean aggregation with fused post-add/relu
__device__ inline void d_agg(int bid,
    const u16* feat, const int* csr, const int* base, const int* cnt,
    const u16* post, void* out, int outF32, int doRelu, int n)
{
  int lr = threadIdx.x & 15;
  int grp = threadIdx.x >> 4;           // 0..15
  int gv = bid * 16 + grp;
  if (gv >= n) return;
  int b = base[gv], c = cnt[gv];
  float s0=0,s1=0,s2=0,s3=0,s4=0,s5=0,s6=0,s7=0;
  for (int i = 0; i < c; i += 8) {
    int m = c - i;
    int idx[8];
#pragma unroll
    for (int u = 0; u < 8; u++) idx[u] = csr[b + i + min(u, m - 1)];
#pragma unroll
    for (int u = 0; u < 8; u++) {
      uint4 v = ((const uint4*)(feat + (size_t)idx[u] * 128))[lr];
      if (u < m) {
        s0 += bf_lo(v.x); s1 += bf_hi(v.x);
        s2 += bf_lo(v.y); s3 += bf_hi(v.y);
        s4 += bf_lo(v.z); s5 += bf_hi(v.z);
        s6 += bf_lo(v.w); s7 += bf_hi(v.w);
      }
    }
  }
  float inv = (c > 0) ? 1.0f / (float)c : 0.0f;
  s0 *= inv; s1 *= inv; s2 *= inv; s3 *= inv;
  s4 *= inv; s5 *= inv; s6 *= inv; s7 *= inv;
  if (post) {
    uint4 p = ((const uint4*)(post + (size_t)gv * 128))[lr];
    s0 += bf_lo(p.x); s1 += bf_hi(p.x);
    s2 += bf_lo(p.y); s3 += bf_hi(p.y);
    s4 += bf_lo(p.z); s5 += bf_hi(p.z);
    s6 += bf_lo(p.w); s7 += bf_hi(p.w);
  }
  if (doRelu) {
    s0 = fmaxf(s0, 0.f); s1 = fmaxf(s1, 0.f);
    s2 = fmaxf(s2, 0.f); s3 = fmaxf(s3, 0.f);
    s4 = fmaxf(s4, 0.f); s5 = fmaxf(s5, 0.f);
    s6 = fmaxf(s6, 0.f); s7 = fmaxf(s7, 0.f);
  }
  if (outF32) {
    float* op = (float*)out + (size_t)gv * 128 + lr * 8;
    *(float4*)op = make_float4(s0, s1, s2, s3);
    *(float4*)(op + 4) = make_float4(s4, s5, s6, s7);
  } else {
    uint4 o;
    o.x = pack2(s0, s1); o.y = pack2(s2, s3);
    o.z = pack2(s4, s5); o.w = pack2(s6, s7);
    ((uint4*)((u16*)out + (size_t)gv * 128))[lr] = o;
  }
}

// B-resident MFMA GEMM: C[M,128] = act( A@W (+Dadd_f32) (+bias) ), K=128
__device__ inline void d_gemm(int bid, int nb,
    const u16* A, const u16* Wt, const float* bias, const float* Dadd,
    void* Cout, int M, int doRelu, int outF32)
{
  int lane = threadIdx.x & 63;
  int r = lane & 15, q = lane >> 4;
  int wid = (bid * 256 + threadIdx.x) >> 6;
  int nw = nb * 4;

  bfrag B[4][8];
#pragma unroll
  for (int k0 = 0; k0 < 4; k0++)
#pragma unroll
    for (int j = 0; j < 8; j++)
      B[k0][j] = *(const bfrag*)(Wt + (size_t)(j * 16 + r) * 128 + k0 * 32 + q * 8);

  for (int strip = wid; strip * 16 < M; strip += nw) {
    const u16* arow = A + (size_t)(strip * 16 + r) * 128 + q * 8;
    bfrag a0 = *(const bfrag*)(arow);
    bfrag a1 = *(const bfrag*)(arow + 32);
    bfrag a2 = *(const bfrag*)(arow + 64);
    bfrag a3 = *(const bfrag*)(arow + 96);

    ffrag acc[8];
#pragma unroll
    for (int j = 0; j < 8; j++) acc[j] = (ffrag)0.f;
#pragma unroll
    for (int j = 0; j < 8; j++)
      acc[j] = __builtin_amdgcn_mfma_f32_16x16x32_bf16(B[0][j], a0, acc[j], 0, 0, 0);
#pragma unroll
    for (int j = 0; j < 8; j++)
      acc[j] = __builtin_amdgcn_mfma_f32_16x16x32_bf16(B[1][j], a1, acc[j], 0, 0, 0);
#pragma unroll
    for (int j = 0; j < 8; j++)
      acc[j] = __builtin_amdgcn_mfma_f32_16x16x32_bf16(B[2][j], a2, acc[j], 0, 0, 0);
#pragma unroll
    for (int j = 0; j < 8; j++)
      acc[j] = __builtin_amdgcn_mfma_f32_16x16x32_bf16(B[3][j], a3, acc[j], 0, 0, 0);

    size_t row = (size_t)(strip * 16 + r);
#pragma unroll
    for (int j = 0; j < 8; j++) {
      int col0 = j * 16 + q * 4;
      float v0 = acc[j][0], v1 = acc[j][1], v2 = acc[j][2], v3 = acc[j][3];
      if (bias) {
        float4 bv = *(const float4*)(bias + col0);
        v0 += bv.x; v1 += bv.y; v2 += bv.z; v3 += bv.w;
      }
      if (Dadd) {
        float4 dv = *(const float4*)(Dadd + row * 128 + col0);
        v0 += dv.x; v1 += dv.y; v2 += dv.z; v3 += dv.w;
      }
      if (doRelu) {
        v0 = fmaxf(v0, 0.f); v1 = fmaxf(v1, 0.f);
        v2 = fmaxf(v2, 0.f); v3 = fmaxf(v3, 0.f);
      }
      if (outF32) {
        *(float4*)((float*)Cout + row * 128 + col0) = make_float4(v0, v1, v2, v3);
      } else {
        ushort4 o;
        o.x = f2bf(v0); o.y = f2bf(v1); o.z = f2bf(v2); o.w = f2bf(v3);
        *(ushort4*)((u16*)Cout + row * 128 + col0) = o;
      }
    }
  }
}

// ======================= fat kernels =======================================

// L1: prep || hist
__global__ __launch_bounds__(256) void fat_prep_hist_k(
    const float* w0, const float* w1, const float* w2, const float* w3,
    const float* w4, const float* w5, const float* w6, const float* w7,
    u16* Wt, const float* song_x, u16* xs, int ns4,
    const float* emb, const int* pid, u16* xp, int np,
    const int* es, const int* ep, int* cnt_s, int* cnt_p, int e,
    int nbPrep, int nbHist)
{
  int b = blockIdx.x;
  if (b < nbPrep) {
    d_prep(b, nbPrep, w0, w1, w2, w3, w4, w5, w6, w7,
           Wt, song_x, xs, ns4, emb, pid, xp, np);
  } else {
    d_hist(b - nbPrep, nbHist, es, ep, cnt_s, cnt_p, e);
  }
}

// base prefix (per-block scan, global atomic grab)
__global__ __launch_bounds__(256) void base2_k(
    const int* __restrict__ cnt_p, int* __restrict__ base_p, int* __restrict__ cur_p,
    const int* __restrict__ cnt_s, int* __restrict__ base_s, int* __restrict__ cur_s,
    int* __restrict__ gcnt, int np, int ns, int nbp)
{
  __shared__ int sh[256];
  __shared__ int bb;
  int t = threadIdx.x;
  const int* cnt; int* base; int* cur; int* gc; int n; int i;
  if ((int)blockIdx.x < nbp) {
    cnt = cnt_p; base = base_p; cur = cur_p; gc = gcnt; n = np;
    i = blockIdx.x * 256 + t;
  } else {
    cnt = cnt_s; base = base_s; cur = cur_s; gc = gcnt + 1; n = ns;
    i = (blockIdx.x - nbp) * 256 + t;
  }
  int v = (i < n) ? cnt[i] : 0;
  sh[t] = v;
  __syncthreads();
  for (int off = 1; off < 256; off <<= 1) {
    int tv = (t >= off) ? sh[t - off] : 0;
    __syncthreads();
    sh[t] += tv;
    __syncthreads();
  }
  if (t == 255) bb = atomicAdd(gc, sh[255]);
  __syncthreads();
  if (i < n) {
    int e = bb + sh[t] - v;
    base[i] = e;
    cur[i] = e;
  }
}

// L3: place || gemm || gemm
__global__ __launch_bounds__(256, 2) void fat_place_gg_k(
    const int* es, const int* ep, int* cur_s, int* cur_p,
    int* csr_s, int* csr_p, int e, int nbPlace,
    const u16* A1, const u16* W1, const float* bias1, void* C1, int M1, int nb1,
    const u16* A2, const u16* W2, const float* bias2, void* C2, int M2, int nb2)
{
  int b = blockIdx.x;
  if (b < nbPlace) {
    d_place(b, nbPlace, es, ep, cur_s, cur_p, csr_s, csr_p, e);
  } else if (b < nbPlace + nb1) {
    d_gemm(b - nbPlace, nb1, A1, W1, bias1, nullptr, C1, M1, 0, 0);
  } else {
    d_gemm(b - nbPlace - nb1, nb2, A2, W2, bias2, nullptr, C2, M2, 0, 0);
  }
}

// L4: agg || agg
__global__ __launch_bounds__(256) void fat_aa_k(
    const u16* f1, const int* c1, const int* b1, const int* n1v,
    const u16* p1, void* o1, int of1, int r1, int nn1, int nb1,
    const u16* f2, const int* c2, const int* b2, const int* n2v,
    const u16* p2, void* o2, int of2, int r2, int nn2)
{
  int b = blockIdx.x;
  if (b < nb1) d_agg(b, f1, c1, b1, n1v, p1, o1, of1, r1, nn1);
  else         d_agg(b - nb1, f2, c2, b2, n2v, p2, o2, of2, r2, nn2);
}

// L5/L7: gemm || gemm
__global__ __launch_bounds__(256, 2) void fat_gg_k(
    const u16* A1, const u16* W1, const float* bias1, const float* D1,
    void* C1, int M1, int r1, int of1, int nb1,
    const u16* A2, const u16* W2, const float* bias2, const float* D2,
    void* C2, int M2, int r2, int of2, int nb2)
{
  int b = blockIdx.x;
  if (b < nb1) d_gemm(b, nb1, A1, W1, bias1, D1, C1, M1, r1, of1);
  else         d_gemm(b - nb1, nb2, A2, W2, bias2, D2, C2, M2, r2, of2);
}

// L6/L8: gemm || agg (gemm blocks first so they're resident early)
__global__ __launch_bounds__(256, 2) void fat_ga_k(
    const u16* A1, const u16* W1, const float* bias1, const float* D1,
    void* C1, int M1, int r1, int of1, int nb1,
    const u16* f2, const int* c2, const int* b2, const int* n2v,
    const u16* p2, void* o2, int of2, int r2, int nn2)
{
  int b = blockIdx.x;
  if (b < nb1) d_gemm(b, nb1, A1, W1, bias1, D1, C1, M1, r1, of1);
  else         d_agg(b - nb1, f2, c2, b2, n2v, p2, o2, of2, r2, nn2);
}

// ---------------------------------------------------------------------------

extern "C" void kernel_launch(void* const* d_in, const int* in_sizes, int n_in,
                              void* d_out, int out_size, void* d_ws, size_t ws_size,
                              hipStream_t stream)
{
  const float* song_x = (const float*)d_in[0];
  const int*   pid    = (const int*)d_in[1];
  const int*   e_song = (const int*)d_in[2];
  const int*   e_play = (const int*)d_in[3];
  const float* emb    = (const float*)d_in[4];
  const float* Wl1_sp = (const float*)d_in[5];
  const float* Wr1_sp = (const float*)d_in[6];
  const float* b1_sp  = (const float*)d_in[7];
  const float* Wl1_ps = (const float*)d_in[8];
  const float* Wr1_ps = (const float*)d_in[9];
  const float* b1_ps  = (const float*)d_in[10];
  const float* Wl2_sp = (const float*)d_in[11];
  const float* Wr2_sp = (const float*)d_in[12];
  const float* b2_sp  = (const float*)d_in[13];
  const float* Wl2_ps = (const float*)d_in[14];
  const float* Wr2_ps = (const float*)d_in[15];
  const float* b2_ps  = (const float*)d_in[16];

  const int NS = in_sizes[0] / 128;
  const int NP = in_sizes[1];
  const int E  = in_sizes[2];

  char* w = (char*)d_ws;
  auto alloc = [&](size_t bytes) { char* p = w; w += ws_align(bytes); return p; };
  u16* x_play = (u16*)alloc((size_t)NP * 128 * 2);
  u16* Ms     = (u16*)alloc((size_t)NP * 128 * 2);
  u16* yp     = (u16*)alloc((size_t)NP * 128 * 2);
  u16* p1     = (u16*)alloc((size_t)NP * 128 * 2);
  u16* s1     = (u16*)alloc((size_t)NS * 128 * 2);
  u16* xs     = (u16*)alloc((size_t)NS * 128 * 2);
  u16* Gs     = (u16*)alloc((size_t)NS * 128 * 2);
  float* Gp   = (float*)alloc((size_t)NP * 128 * 4);
  u16* Wt     = (u16*)alloc((size_t)8 * 16384 * 2);  // [mat][n][k]
  int* cnt_p = (int*)alloc(((size_t)NP + NS + 2) * 4);
  int* cnt_s = cnt_p + NP;
  int* gcnt  = cnt_s + NS;       // 2 ints
  int* base_p = (int*)alloc((size_t)NP * 4);
  int* cur_p  = (int*)alloc((size_t)NP * 4);
  int* base_s = (int*)alloc((size_t)NS * 4);
  int* cur_s  = (int*)alloc((size_t)NS * 4);
  int* csr_p  = (int*)alloc((size_t)E * 4);
  int* csr_s  = (int*)alloc((size_t)E * 4);

  float* s2_out = (float*)d_out;
  float* p2_out = (float*)d_out + (size_t)NS * 128;

  u16* Wt_l1sp = Wt + 0 * 16384;
  u16* Wt_r1sp = Wt + 1 * 16384;
  u16* Wt_l1ps = Wt + 2 * 16384;
  u16* Wt_r1ps = Wt + 3 * 16384;
  u16* Wt_l2sp = Wt + 4 * 16384;
  u16* Wt_r2sp = Wt + 5 * 16384;
  u16* Wt_l2ps = Wt + 6 * 16384;
  u16* Wt_r2ps = Wt + 7 * 16384;

  auto ggrid = [](int M) { int s = M / 16; return (s + 7) / 8; };
  const int gP = ggrid(NP), gS = ggrid(NS);        // 157, 782
  const int aggP_b = (NP + 15) / 16;               // 1250
  const int aggS_b = (NS + 15) / 16;               // 6250
  const int nbp = (NP + 255) / 256, nbs = (NS + 255) / 256;
  const int nbPrep = 1024, nbHist = 512, nbPlace = 512;

  // ---- zero counters (capture-safe async memset) ----
  hipMemsetAsync(cnt_p, 0, ((size_t)NP + NS + 2) * 4, stream);

  // ---- L1: prep || hist ----
  fat_prep_hist_k<<<nbPrep + nbHist, 256, 0, stream>>>(
      Wl1_sp, Wr1_sp, Wl1_ps, Wr1_ps, Wl2_sp, Wr2_sp, Wl2_ps, Wr2_ps, Wt,
      song_x, xs, NS * 32, emb, pid, x_play, NP,
      e_song, e_play, cnt_s, cnt_p, E, nbPrep, nbHist);

  // ---- L2: base prefix ----
  base2_k<<<nbp + nbs, 256, 0, stream>>>(cnt_p, base_p, cur_p,
                                         cnt_s, base_s, cur_s, gcnt, NP, NS, nbp);

  // ---- L3: place || yp1 = x_play@Wl1_ps || Gs1 = xs@Wr1_ps + b1_ps ----
  fat_place_gg_k<<<nbPlace + gP + gS, 256, 0, stream>>>(
      e_song, e_play, cur_s, cur_p, csr_s, csr_p, E, nbPlace,
      x_play, Wt_l1ps, nullptr, yp, NP, gP,
      xs, Wt_r1ps, b1_ps, (void*)Gs, NS, gS);

  // ---- L4: s1 = relu(mean_s(yp)+Gs) || Ms1 = mean_p(xs) ----
  fat_aa_k<<<aggS_b + aggP_b, 256, 0, stream>>>(
      yp, csr_s, base_s, cnt_s, Gs, (void*)s1, 0, 1, NS, aggS_b,
      xs, csr_p, base_p, cnt_p, nullptr, (void*)Ms, 0, 0, NP);

  // ---- L5: Gs2 = s1@Wr2_ps + b2_ps || Gp1 = Ms@Wl1_sp (f32) ----
  fat_gg_k<<<gS + gP, 256, 0, stream>>>(
      s1, Wt_r2ps, b2_ps, nullptr, (void*)Gs, NS, 0, 0, gS,
      Ms, Wt_l1sp, nullptr, nullptr, (void*)Gp, NP, 0, 1, gP);

  // ---- L6: p1 = relu(x_play@Wr1_sp + b1_sp + Gp) || Ms2 = mean_p(s1) ----
  fat_ga_k<<<gP + aggP_b, 256, 0, stream>>>(
      x_play, Wt_r1sp, b1_sp, Gp, (void*)p1, NP, 1, 0, gP,
      s1, csr_p, base_p, cnt_p, nullptr, (void*)Ms, 0, 0, NP);

  // ---- L7: yp2 = p1@Wl2_ps || Gp2 = Ms@Wl2_sp (f32) ----
  fat_gg_k<<<gP + gP, 256, 0, stream>>>(
      p1, Wt_l2ps, nullptr, nullptr, (void*)yp, NP, 0, 0, gP,
      Ms, Wt_l2sp, nullptr, nullptr, (void*)Gp, NP, 0, 1, gP);

  // ---- L8: p2 = p1@Wr2_sp + b2_sp + Gp (f32) || s2 = mean_s(yp)+Gs (f32) --
  fat_ga_k<<<gP + aggS_b, 256, 0, stream>>>(
      p1, Wt_r2sp, b2_sp, Gp, (void*)p2_out, NP, 0, 1, gP,
      yp, csr_s, base_s, cnt_s, Gs, (void*)s2_out, 1, 0, NS);
}